// Round 2
// baseline (943.682 us; speedup 1.0000x reference)
//
#include <hip/hip_runtime.h>
#include <hip/hip_bf16.h>

// FrozenBNBEmbedding: dequantize-blockwise (int8 codes -> fp32 via 256-entry LUT,
// per-4096-block absmax scale) fused with embedding gather.
// DIM == BLOCK == 4096  =>  one absmax scale per vocab row.
//
// R1: 2 rows/block (8 int4 loads in flight before any dependent LDS lookup),
// nontemporal float4 stores (out is write-once, never re-read).

#define DIM 4096

typedef float f32x4 __attribute__((ext_vector_type(4)));

__global__ __launch_bounds__(256) void bnb_embed_kernel(
    const int* __restrict__ tokens,    // [n_tokens] token ids
    const int* __restrict__ weight,    // [VOCAB, DIM] int8 codes stored as int32
    const float* __restrict__ absmax,  // [VOCAB] per-row scale (n_blocks == VOCAB)
    const float* __restrict__ code,    // [256] LUT
    float* __restrict__ out,           // [n_tokens, DIM] fp32
    int n_tokens)
{
    __shared__ float lut[256];
    lut[threadIdx.x] = code[threadIdx.x];
    __syncthreads();

    const int base = blockIdx.x * 2;   // 2 rows per block
    if (base >= n_tokens) return;

    const int t0 = tokens[base];
    const int t1 = tokens[base + 1];
    const float s0 = absmax[t0];
    const float s1 = absmax[t1];

    const int4* __restrict__ w0 = (const int4*)(weight + (size_t)t0 * DIM);
    const int4* __restrict__ w1 = (const int4*)(weight + (size_t)t1 * DIM);
    f32x4* __restrict__ o0 = (f32x4*)(out + (size_t)base * DIM);
    f32x4* __restrict__ o1 = o0 + DIM / 4;

    // Issue all 8 independent 16B loads before any dependent use.
    int4 q0[4], q1[4];
#pragma unroll
    for (int i = 0; i < 4; ++i) q0[i] = w0[threadIdx.x + i * 256];
#pragma unroll
    for (int i = 0; i < 4; ++i) q1[i] = w1[threadIdx.x + i * 256];

#pragma unroll
    for (int i = 0; i < 4; ++i) {
        const int idx = threadIdx.x + i * 256;
        f32x4 o;
        o.x = lut[q0[i].x & 255] * s0;
        o.y = lut[q0[i].y & 255] * s0;
        o.z = lut[q0[i].z & 255] * s0;
        o.w = lut[q0[i].w & 255] * s0;
        __builtin_nontemporal_store(o, &o0[idx]);
    }
#pragma unroll
    for (int i = 0; i < 4; ++i) {
        const int idx = threadIdx.x + i * 256;
        f32x4 o;
        o.x = lut[q1[i].x & 255] * s1;
        o.y = lut[q1[i].y & 255] * s1;
        o.z = lut[q1[i].z & 255] * s1;
        o.w = lut[q1[i].w & 255] * s1;
        __builtin_nontemporal_store(o, &o1[idx]);
    }
}

extern "C" void kernel_launch(void* const* d_in, const int* in_sizes, int n_in,
                              void* d_out, int out_size, void* d_ws, size_t ws_size,
                              hipStream_t stream)
{
    const int*   tokens = (const int*)d_in[0];    // [4, 2048] int32
    const int*   weight = (const int*)d_in[1];    // [50400, 4096] int32
    const float* absmax = (const float*)d_in[2];  // [50400] fp32
    const float* code   = (const float*)d_in[3];  // [256] fp32
    float*       out    = (float*)d_out;          // [4, 2048, 4096] fp32

    const int n_tokens = in_sizes[0];             // 8192
    const int grid = (n_tokens + 1) / 2;          // 2 rows per block
    bnb_embed_kernel<<<grid, 256, 0, stream>>>(tokens, weight, absmax, code, out, n_tokens);
}